// Round 4
// baseline (212.153 us; speedup 1.0000x reference)
//
#include <hip/hip_runtime.h>
#include <hip/hip_bf16.h>
#include <stdint.h>

#define T_DIM 12
#define N_DIM 2048
#define B_DIM 16
#define C_IN  64
#define C_OUT 64
#define EMB   16
#define P_DIM 1024   // B_DIM*C_IN

typedef __attribute__((ext_vector_type(8))) short short8;
typedef __attribute__((ext_vector_type(4))) float f32x4;

static __device__ __forceinline__ unsigned short f2bf(float f) {
  union { float f; uint32_t u; } v; v.f = f;
  uint32_t u = v.u;
  return (unsigned short)((u + 0x7fffu + ((u >> 16) & 1u)) >> 16);
}

static __device__ __forceinline__ float sigf(float x) {
  return __builtin_amdgcn_rcpf(1.0f + __expf(-x));
}

// async global->LDS, 16B per lane; lds ptr wave-uniform base (+lane*16 by HW)
static __device__ __forceinline__ void gload16(const void* g, void* l) {
  __builtin_amdgcn_global_load_lds(
      (const __attribute__((address_space(1))) unsigned int*)g,
      (__attribute__((address_space(3))) unsigned int*)l, 16, 0, 0);
}

template<bool MAX>
static __device__ __forceinline__ float block_red(float v, float* red) {
  #pragma unroll
  for (int o = 32; o > 0; o >>= 1) {
    float t = __shfl_down(v, o, 64);
    v = MAX ? fmaxf(v, t) : (v + t);
  }
  __syncthreads();
  if ((threadIdx.x & 63) == 0) red[threadIdx.x >> 6] = v;
  __syncthreads();
  float r = red[0];
  #pragma unroll
  for (int w = 1; w < 4; ++w) r = MAX ? fmaxf(r, red[w]) : (r + red[w]);
  return r;
}

// ---------------- stats: static row-sum d^-1/2, adaptive softmax row max/sumexp
__launch_bounds__(256)
__global__ void k_stats(const float* __restrict__ As, const float* __restrict__ E1,
                        const float* __restrict__ E2, float* __restrict__ dinv,
                        float* __restrict__ mx, float* __restrict__ se) {
  int n = blockIdx.x, tid = threadIdx.x;
  __shared__ float e1s[EMB];
  __shared__ float red[4];
  if (tid < EMB) e1s[tid] = E1[n * EMB + tid];
  __syncthreads();

  float rs = 0.f;
  #pragma unroll
  for (int i = 0; i < N_DIM / 256; ++i)
    rs += fmaxf(As[(size_t)n * N_DIM + i * 256 + tid], 0.f);

  float p[8];
  #pragma unroll
  for (int i = 0; i < 8; ++i) {
    int m = i * 256 + tid;
    float d = 0.f;
    #pragma unroll
    for (int e = 0; e < EMB; ++e) d += e1s[e] * E2[e * N_DIM + m];
    p[i] = fmaxf(d, 0.f);
  }
  float lmx = p[0];
  #pragma unroll
  for (int i = 1; i < 8; ++i) lmx = fmaxf(lmx, p[i]);
  float gmx = block_red<true>(lmx, red);
  float ls = 0.f;
  #pragma unroll
  for (int i = 0; i < 8; ++i) ls += expf(p[i] - gmx);
  float gse = block_red<false>(ls, red);
  float grs = block_red<false>(rs, red);
  if (tid == 0) {
    dinv[n] = rsqrtf(fmaxf(grs + 1.0f, 1e-12f));
    mx[n] = gmx;
    se[n] = gse;
  }
}

// ---------------- W^T (128 x 64) bf16
__launch_bounds__(256)
__global__ void k_wt(const float* __restrict__ W, unsigned short* __restrict__ WT) {
  int q = blockIdx.x * 256 + threadIdx.x;   // 8192
  int j = q >> 6, c = q & 63;
  WT[q] = f2bf(W[c * 128 + j]);
}

// ---------------- assemble A (2048x2048) in bf16
__launch_bounds__(256)
__global__ void k_abuild(const float* __restrict__ As, const float* __restrict__ E1,
                         const float* __restrict__ E2, const float* __restrict__ alpha,
                         const float* __restrict__ dinv, const float* __restrict__ mx,
                         const float* __restrict__ se, unsigned short* __restrict__ A) {
  int n = blockIdx.x, tid = threadIdx.x;
  __shared__ float e1s[EMB];
  if (tid < EMB) e1s[tid] = E1[n * EMB + tid];
  __syncthreads();
  float a = sigf(alpha[0]);
  float di_n = dinv[n], m_n = mx[n], inv_se = 1.f / se[n];
  float ca = a, cb = (1.f - a) * 0.5f;
  #pragma unroll
  for (int i = 0; i < 8; ++i) {
    int m = i * 256 + tid;
    float d = 0.f;
    #pragma unroll
    for (int e = 0; e < EMB; ++e) d += e1s[e] * E2[e * N_DIM + m];
    float soft = expf(fmaxf(d, 0.f) - m_n) * inv_se;
    float idm = (m == n) ? 1.f : 0.f;
    float sv = fmaxf(As[(size_t)n * N_DIM + m], 0.f) + idm;
    float val = ca * di_n * dinv[m] * sv + cb * (soft + idm);
    A[(size_t)n * N_DIM + m] = f2bf(val);
  }
}

// ---------------- x (t,m,p) f32 -> XT (t,p,m) bf16 via LDS tile transpose
__launch_bounds__(256)
__global__ void k_xt(const float* __restrict__ x, unsigned short* __restrict__ XT) {
  __shared__ float tile[64 * 65];
  int bid = blockIdx.x;
  int t = bid >> 9;
  int rem = bid & 511;
  int mt = rem >> 4, pt = rem & 15;
  int m0 = mt * 64, p0 = pt * 64;
  int tid = threadIdx.x;
  #pragma unroll
  for (int i = 0; i < 4; ++i) {
    int lin = i * 256 + tid;
    int mm = lin >> 4;
    int pp4 = lin & 15;
    const float4 v = *(const float4*)&x[(size_t)(t * N_DIM + m0 + mm) * P_DIM + p0 + pp4 * 4];
    tile[(pp4 * 4 + 0) * 65 + mm] = v.x;
    tile[(pp4 * 4 + 1) * 65 + mm] = v.y;
    tile[(pp4 * 4 + 2) * 65 + mm] = v.z;
    tile[(pp4 * 4 + 3) * 65 + mm] = v.w;
  }
  __syncthreads();
  #pragma unroll
  for (int i = 0; i < 2; ++i) {
    int lin = i * 256 + tid;
    int pp = lin >> 3;
    int mmb = (lin & 7) * 8;
    union { unsigned short s[8]; uint4 u; } pk;
    #pragma unroll
    for (int q = 0; q < 8; ++q) pk.s[q] = f2bf(tile[pp * 65 + mmb + q]);
    *(uint4*)&XT[(size_t)t * P_DIM * N_DIM + (size_t)(p0 + pp) * N_DIM + m0 + mmb] = pk.u;
  }
}

// ---------------- fused 8-phase GEMM: Y_t = A @ X_t, then swiglu(Y@Wfc+b)
// BM=256 BN=128 BK=64, 512 threads = 8 waves (4M x 2N), per-wave 64x64 out.
// 3 LDS buffers (depth-2 prefetch), counted vmcnt(6), raw barriers, T2 swizzle.
#define LDS_BUF 49152   // A tile 32KB + B tile 16KB

__launch_bounds__(512, 1)
__global__ void k_gemm(const unsigned short* __restrict__ A,   // 2048x2048 bf16
                       const unsigned short* __restrict__ XT,  // 12 x 1024 x 2048 bf16
                       const unsigned short* __restrict__ WT,  // 128 x 64 bf16
                       const float* __restrict__ bfc,          // 128 f32
                       float* __restrict__ out) {
  __shared__ __align__(16) char lds[3 * LDS_BUF];   // 144 KB

  // XCD-aware bijective swizzle (768 % 8 == 0)
  int cpx = 768 >> 3;
  int bid = (blockIdx.x & 7) * cpx + (blockIdx.x >> 3);
  int t = bid / 64;
  int rem = bid - t * 64;
  int mb = rem >> 3, pb = rem & 7;
  int n0 = mb * 256, p0 = pb * 128;

  int tid = threadIdx.x;
  int lane = tid & 63, wid = tid >> 6;
  int wr = wid >> 1, wc = wid & 1;

  // staging source (pre-swizzled global addr so linear LDS dest = swizzled layout)
  int srow = tid >> 3;                            // 0..63
  int scol = ((tid & 7) ^ (srow & 7)) * 8;        // swizzled k-elems within 64
  const unsigned short* gA = A + (size_t)(n0 + srow) * N_DIM + scol;
  const unsigned short* gB = XT + (size_t)t * P_DIM * N_DIM + (size_t)(p0 + srow) * N_DIM + scol;
  int sdst = wid * 1024;   // this wave's 1KB chunk within an 8KB statement

  // fragment read lane offsets (swizzled): row*(128B) + ((k16*16) ^ ((row&7)<<4))
  int swz = (lane & 7) << 4;
  int aoff0 = (wr * 64 + (lane & 15)) * 128 + (((lane >> 4) * 16) ^ swz);
  int boff0 = (wc * 64 + (lane & 15)) * 128 + (((lane >> 4) * 16) ^ swz);

  f32x4 acc[4][4];
  #pragma unroll
  for (int m = 0; m < 4; ++m)
    #pragma unroll
    for (int n = 0; n < 4; ++n) acc[m][n] = (f32x4){0.f, 0.f, 0.f, 0.f};

  // prologue: stage tile0 -> buf0, tile1 -> buf1 (tile0's 6 loads first)
  #pragma unroll
  for (int q = 0; q < 4; ++q) gload16(gA + (size_t)q * 131072, lds + q * 8192 + sdst);
  #pragma unroll
  for (int q = 0; q < 2; ++q) gload16(gB + (size_t)q * 131072, lds + 32768 + q * 8192 + sdst);
  #pragma unroll
  for (int q = 0; q < 4; ++q) gload16(gA + (size_t)q * 131072 + 64, lds + LDS_BUF + q * 8192 + sdst);
  #pragma unroll
  for (int q = 0; q < 2; ++q) gload16(gB + (size_t)q * 131072 + 64, lds + LDS_BUF + 32768 + q * 8192 + sdst);
  asm volatile("s_waitcnt vmcnt(6)" ::: "memory");
  __builtin_amdgcn_s_barrier();

#define PH(QR, QC, STG, VMW) { \
    short8 fa[2][2], fb[2][2]; \
    _Pragma("unroll") for (int m2 = 0; m2 < 2; ++m2) \
      _Pragma("unroll") for (int kk = 0; kk < 2; ++kk) \
        fa[m2][kk] = *(const short8*)(Ab + ((aoff0 + ((QR) * 2 + m2) * 2048) ^ (kk * 64))); \
    _Pragma("unroll") for (int n2 = 0; n2 < 2; ++n2) \
      _Pragma("unroll") for (int kk = 0; kk < 2; ++kk) \
        fb[n2][kk] = *(const short8*)(Bb + ((boff0 + ((QC) * 2 + n2) * 2048) ^ (kk * 64))); \
    STG; \
    __builtin_amdgcn_s_barrier(); \
    asm volatile("s_waitcnt lgkmcnt(0)" ::: "memory"); \
    __builtin_amdgcn_sched_barrier(0); \
    __builtin_amdgcn_s_setprio(1); \
    _Pragma("unroll") for (int m2 = 0; m2 < 2; ++m2) \
      _Pragma("unroll") for (int n2 = 0; n2 < 2; ++n2) { \
        acc[(QR)*2+m2][(QC)*2+n2] = __builtin_amdgcn_mfma_f32_16x16x32_bf16(fa[m2][0], fb[n2][0], acc[(QR)*2+m2][(QC)*2+n2], 0, 0, 0); \
        acc[(QR)*2+m2][(QC)*2+n2] = __builtin_amdgcn_mfma_f32_16x16x32_bf16(fa[m2][1], fb[n2][1], acc[(QR)*2+m2][(QC)*2+n2], 0, 0, 0); \
      } \
    __builtin_amdgcn_s_setprio(0); \
    VMW; \
    __builtin_amdgcn_s_barrier(); }

  int buf = 0;
  int koff = 128;   // k-elem base of tile j+2
  for (int j = 0; j < 32; ++j) {
    const char* Ab = lds + buf * LDS_BUF;
    const char* Bb = Ab + 32768;
    int bufn = buf + 2; if (bufn >= 3) bufn -= 3;
    char* An = lds + bufn * LDS_BUF;
    char* Bn = An + 32768;
    bool st = (j < 30);

    PH(0, 0,
       if (st) { gload16(gA + koff, An + sdst);
                 gload16(gA + 131072 + koff, An + 8192 + sdst); }, )
    PH(0, 1,
       if (st) { gload16(gA + 262144 + koff, An + 16384 + sdst);
                 gload16(gA + 393216 + koff, An + 24576 + sdst); }, )
    PH(1, 0,
       if (st) { gload16(gB + koff, Bn + sdst);
                 gload16(gB + 131072 + koff, Bn + 8192 + sdst); }, )
    PH(1, 1, ,
       if (st) { asm volatile("s_waitcnt vmcnt(6)" ::: "memory"); }
       else    { asm volatile("s_waitcnt vmcnt(0)" ::: "memory"); })

    buf = (buf + 1 == 3) ? 0 : buf + 1;
    koff += 64;
  }
#undef PH

  // ---- epilogue: Ys (512 rows x 64 c, bf16, XOR-swizzled 128B rows) overlays buf0/1
  #pragma unroll
  for (int m = 0; m < 4; ++m) {
    #pragma unroll
    for (int n = 0; n < 4; ++n) {
      #pragma unroll
      for (int reg = 0; reg < 4; ++reg) {
        int row = wr * 64 + m * 16 + ((lane >> 4) << 2) + reg;  // n_local 0..255
        int nb = row * 2 + wc;                                  // (n,b) row 0..511
        int c = n * 16 + (lane & 15);
        int byte = nb * 128 + ((c * 2) ^ ((nb & 7) << 4));
        *(unsigned short*)(lds + byte) = f2bf(acc[m][n][reg]);
      }
    }
  }
  __syncthreads();

  // GEMM2: (512 x 64) @ (64 x 128) + b, swiglu. W^T from global (L2-hot).
  short8 wf0[8], wf1[8];
  float bl[8];
  #pragma unroll
  for (int f2 = 0; f2 < 8; ++f2) {
    int jc = f2 * 16 + (lane & 15);
    wf0[f2] = *(const short8*)((const char*)WT + jc * 128 + (lane >> 4) * 16);
    wf1[f2] = *(const short8*)((const char*)WT + jc * 128 + 64 + (lane >> 4) * 16);
    bl[f2] = bfc[jc];
  }

  int ys0 = (lane & 15) * 128 + (((lane >> 4) * 16) ^ swz);
  int b0 = pb * 2;
  #pragma unroll
  for (int r2 = 0; r2 < 4; ++r2) {
    int rowbase = wid * 64 + r2 * 16;
    short8 a0 = *(const short8*)(lds + (rowbase * 128 + ys0));
    short8 a1 = *(const short8*)(lds + ((rowbase * 128 + ys0) ^ 64));
    f32x4 acc2[8];
    #pragma unroll
    for (int f2 = 0; f2 < 8; ++f2) {
      acc2[f2] = (f32x4){0.f, 0.f, 0.f, 0.f};
      acc2[f2] = __builtin_amdgcn_mfma_f32_16x16x32_bf16(a0, wf0[f2], acc2[f2], 0, 0, 0);
      acc2[f2] = __builtin_amdgcn_mfma_f32_16x16x32_bf16(a1, wf1[f2], acc2[f2], 0, 0, 0);
    }
    #pragma unroll
    for (int f2 = 0; f2 < 4; ++f2) {
      #pragma unroll
      for (int reg = 0; reg < 4; ++reg) {
        int nb = rowbase + ((lane >> 4) << 2) + reg;
        float zl = acc2[f2][reg] + bl[f2];
        float zr = acc2[f2 + 4][reg] + bl[f2 + 4];
        float ov = zl * sigf(zr);
        int n = n0 + (nb >> 1);
        int b = b0 + (nb & 1);
        int co = f2 * 16 + (lane & 15);
        out[(size_t)((t * N_DIM + n) * B_DIM + b) * C_OUT + co] = ov;
      }
    }
  }
}

extern "C" void kernel_launch(void* const* d_in, const int* in_sizes, int n_in,
                              void* d_out, int out_size, void* d_ws, size_t ws_size,
                              hipStream_t stream) {
  const float* x  = (const float*)d_in[0];
  const float* As = (const float*)d_in[1];
  const float* E1 = (const float*)d_in[2];
  const float* E2 = (const float*)d_in[3];
  const float* al = (const float*)d_in[4];
  const float* W  = (const float*)d_in[5];
  const float* bf = (const float*)d_in[6];
  float* out = (float*)d_out;

  char* ws = (char*)d_ws;
  unsigned short* XT = (unsigned short*)ws;                       // 50,331,648 B
  unsigned short* Ab = (unsigned short*)(ws + 50331648);          //  8,388,608 B
  unsigned short* WT = (unsigned short*)(ws + 58720256);          //     16,384 B
  float* dinv = (float*)(ws + 58736640);
  float* mx   = (float*)(ws + 58744832);
  float* se   = (float*)(ws + 58753024);

  k_stats<<<dim3(2048), dim3(256), 0, stream>>>(As, E1, E2, dinv, mx, se);
  k_wt<<<dim3(32), dim3(256), 0, stream>>>(W, WT);
  k_abuild<<<dim3(2048), dim3(256), 0, stream>>>(As, E1, E2, al, dinv, mx, se, Ab);
  k_xt<<<dim3(6144), dim3(256), 0, stream>>>(x, XT);
  k_gemm<<<dim3(768), dim3(512), 0, stream>>>(Ab, XT, WT, bf, out);
}

// Round 5
// 210.214 us; speedup vs baseline: 1.0092x; 1.0092x over previous
//
#include <hip/hip_runtime.h>
#include <hip/hip_bf16.h>
#include <stdint.h>

#define T_DIM 12
#define N_DIM 2048
#define B_DIM 16
#define C_IN  64
#define C_OUT 64
#define EMB   16
#define P_DIM 1024   // B_DIM*C_IN

typedef __attribute__((ext_vector_type(8))) short short8;
typedef __attribute__((ext_vector_type(4))) float f32x4;

static __device__ __forceinline__ unsigned short f2bf(float f) {
  union { float f; uint32_t u; } v; v.f = f;
  uint32_t u = v.u;
  return (unsigned short)((u + 0x7fffu + ((u >> 16) & 1u)) >> 16);
}

static __device__ __forceinline__ float sigf(float x) {
  return __builtin_amdgcn_rcpf(1.0f + __expf(-x));
}

// async global->LDS, 16B per lane; lds ptr wave-uniform base (+lane*16 by HW)
static __device__ __forceinline__ void gload16(const void* g, void* l) {
  __builtin_amdgcn_global_load_lds(
      (const __attribute__((address_space(1))) unsigned int*)g,
      (__attribute__((address_space(3))) unsigned int*)l, 16, 0, 0);
}

template<bool MAX>
static __device__ __forceinline__ float block_red(float v, float* red) {
  #pragma unroll
  for (int o = 32; o > 0; o >>= 1) {
    float t = __shfl_down(v, o, 64);
    v = MAX ? fmaxf(v, t) : (v + t);
  }
  __syncthreads();
  if ((threadIdx.x & 63) == 0) red[threadIdx.x >> 6] = v;
  __syncthreads();
  float r = red[0];
  #pragma unroll
  for (int w = 1; w < 4; ++w) r = MAX ? fmaxf(r, red[w]) : (r + red[w]);
  return r;
}

// ---------------- stats: static row-sum d^-1/2, adaptive softmax row max/sumexp
__launch_bounds__(256)
__global__ void k_stats(const float* __restrict__ As, const float* __restrict__ E1,
                        const float* __restrict__ E2, float* __restrict__ dinv,
                        float* __restrict__ mx, float* __restrict__ se) {
  int n = blockIdx.x, tid = threadIdx.x;
  __shared__ float e1s[EMB];
  __shared__ float red[4];
  if (tid < EMB) e1s[tid] = E1[n * EMB + tid];
  __syncthreads();

  float rs = 0.f;
  #pragma unroll
  for (int i = 0; i < N_DIM / 256; ++i)
    rs += fmaxf(As[(size_t)n * N_DIM + i * 256 + tid], 0.f);

  float p[8];
  #pragma unroll
  for (int i = 0; i < 8; ++i) {
    int m = i * 256 + tid;
    float d = 0.f;
    #pragma unroll
    for (int e = 0; e < EMB; ++e) d += e1s[e] * E2[e * N_DIM + m];
    p[i] = fmaxf(d, 0.f);
  }
  float lmx = p[0];
  #pragma unroll
  for (int i = 1; i < 8; ++i) lmx = fmaxf(lmx, p[i]);
  float gmx = block_red<true>(lmx, red);
  float ls = 0.f;
  #pragma unroll
  for (int i = 0; i < 8; ++i) ls += expf(p[i] - gmx);
  float gse = block_red<false>(ls, red);
  float grs = block_red<false>(rs, red);
  if (tid == 0) {
    dinv[n] = rsqrtf(fmaxf(grs + 1.0f, 1e-12f));
    mx[n] = gmx;
    se[n] = gse;
  }
}

// ---------------- W^T (128 x 64) bf16
__launch_bounds__(256)
__global__ void k_wt(const float* __restrict__ W, unsigned short* __restrict__ WT) {
  int q = blockIdx.x * 256 + threadIdx.x;   // 8192
  int j = q >> 6, c = q & 63;
  WT[q] = f2bf(W[c * 128 + j]);
}

// ---------------- assemble A (2048x2048) in bf16
__launch_bounds__(256)
__global__ void k_abuild(const float* __restrict__ As, const float* __restrict__ E1,
                         const float* __restrict__ E2, const float* __restrict__ alpha,
                         const float* __restrict__ dinv, const float* __restrict__ mx,
                         const float* __restrict__ se, unsigned short* __restrict__ A) {
  int n = blockIdx.x, tid = threadIdx.x;
  __shared__ float e1s[EMB];
  if (tid < EMB) e1s[tid] = E1[n * EMB + tid];
  __syncthreads();
  float a = sigf(alpha[0]);
  float di_n = dinv[n], m_n = mx[n], inv_se = 1.f / se[n];
  float ca = a, cb = (1.f - a) * 0.5f;
  #pragma unroll
  for (int i = 0; i < 8; ++i) {
    int m = i * 256 + tid;
    float d = 0.f;
    #pragma unroll
    for (int e = 0; e < EMB; ++e) d += e1s[e] * E2[e * N_DIM + m];
    float soft = expf(fmaxf(d, 0.f) - m_n) * inv_se;
    float idm = (m == n) ? 1.f : 0.f;
    float sv = fmaxf(As[(size_t)n * N_DIM + m], 0.f) + idm;
    float val = ca * di_n * dinv[m] * sv + cb * (soft + idm);
    A[(size_t)n * N_DIM + m] = f2bf(val);
  }
}

// ---------------- x (t,m,p) f32 -> XT (t,p,m) bf16 via LDS tile transpose
__launch_bounds__(256)
__global__ void k_xt(const float* __restrict__ x, unsigned short* __restrict__ XT) {
  __shared__ float tile[64 * 65];
  int bid = blockIdx.x;
  int t = bid >> 9;
  int rem = bid & 511;
  int mt = rem >> 4, pt = rem & 15;
  int m0 = mt * 64, p0 = pt * 64;
  int tid = threadIdx.x;
  #pragma unroll
  for (int i = 0; i < 4; ++i) {
    int lin = i * 256 + tid;
    int mm = lin >> 4;
    int pp4 = lin & 15;
    const float4 v = *(const float4*)&x[(size_t)(t * N_DIM + m0 + mm) * P_DIM + p0 + pp4 * 4];
    tile[(pp4 * 4 + 0) * 65 + mm] = v.x;
    tile[(pp4 * 4 + 1) * 65 + mm] = v.y;
    tile[(pp4 * 4 + 2) * 65 + mm] = v.z;
    tile[(pp4 * 4 + 3) * 65 + mm] = v.w;
  }
  __syncthreads();
  #pragma unroll
  for (int i = 0; i < 2; ++i) {
    int lin = i * 256 + tid;
    int pp = lin >> 3;
    int mmb = (lin & 7) * 8;
    union { unsigned short s[8]; uint4 u; } pk;
    #pragma unroll
    for (int q = 0; q < 8; ++q) pk.s[q] = f2bf(tile[pp * 65 + mmb + q]);
    *(uint4*)&XT[(size_t)t * P_DIM * N_DIM + (size_t)(p0 + pp) * N_DIM + m0 + mmb] = pk.u;
  }
}

// ---------------- fused GEMM (m201 geometry): Y_t = A @ X_t, then swiglu(Y@Wfc+b)
// BM=BN=256, BK=64, 512 thr = 8 waves (2M x 4N), per-wave 128x64 out.
// 2 LDS buffers (64KB each), burst-stage tile j+1 at phase 0 of iter j,
// single vmcnt(0) drain per iter, 4 phases x 16 MFMA, T2 swizzle, T5 setprio.

__launch_bounds__(512, 2)
__global__ void k_gemm(const unsigned short* __restrict__ A,   // 2048x2048 bf16
                       const unsigned short* __restrict__ XT,  // 12 x 1024 x 2048 bf16
                       const unsigned short* __restrict__ WT,  // 128 x 64 bf16
                       const float* __restrict__ bfc,          // 128 f32
                       float* __restrict__ out) {
  __shared__ __align__(16) char lds[131072];   // 128 KB

  // XCD-aware bijective swizzle (384 % 8 == 0)
  int bid = (blockIdx.x & 7) * 48 + (blockIdx.x >> 3);
  int t = bid >> 5;
  int rem = bid & 31;
  int mb = rem >> 2, pb = rem & 3;
  int n0 = mb * 256, p0 = pb * 256;

  int tid = threadIdx.x;
  int lane = tid & 63, wid = tid >> 6;
  int wr = wid >> 2, wc = wid & 3;      // 2M x 4N

  // staging source (pre-swizzled global addr -> linear LDS dest = swizzled layout)
  int srow = tid >> 3;                            // 0..63
  int scol = ((tid & 7) ^ (srow & 7)) * 8;        // swizzled k-chunk within 64
  const unsigned short* gA = A + (size_t)(n0 + srow) * N_DIM + scol;
  const unsigned short* gB = XT + (size_t)t * P_DIM * N_DIM + (size_t)(p0 + srow) * N_DIM + scol;
  int wsd = wid * 1024;    // wave chunk within an 8KB statement

  // fragment read offsets (swizzled rows of 128B)
  int swz = (lane & 7) << 4;
  int aoff0 = (wr * 128 + (lane & 15)) * 128 + (((lane >> 4) * 16) ^ swz);
  int boff0 = (wc * 64 + (lane & 15)) * 128 + (((lane >> 4) * 16) ^ swz);

  f32x4 acc[8][4];
  #pragma unroll
  for (int m = 0; m < 8; ++m)
    #pragma unroll
    for (int n = 0; n < 4; ++n) acc[m][n] = (f32x4){0.f, 0.f, 0.f, 0.f};

  // prologue: stage tile 0 -> buf0 (4 A stmts + 4 B stmts, 8KB each)
  #pragma unroll
  for (int s = 0; s < 4; ++s) gload16(gA + s * 131072, lds + s * 8192 + wsd);
  #pragma unroll
  for (int s = 0; s < 4; ++s) gload16(gB + s * 131072, lds + 32768 + s * 8192 + wsd);
  asm volatile("s_waitcnt vmcnt(0)" ::: "memory");
  __builtin_amdgcn_s_barrier();

#define READ_FA(MQ) \
    _Pragma("unroll") for (int mi = 0; mi < 2; ++mi) \
      _Pragma("unroll") for (int kk = 0; kk < 2; ++kk) \
        fa[mi][kk] = *(const short8*)(Ab + ((aoff0 + ((MQ) * 2 + mi) * 2048) ^ (kk * 64)));

#define MFMAS(MQ) \
    _Pragma("unroll") for (int mi = 0; mi < 2; ++mi) \
      _Pragma("unroll") for (int n = 0; n < 4; ++n) { \
        acc[(MQ)*2+mi][n] = __builtin_amdgcn_mfma_f32_16x16x32_bf16(fa[mi][0], fb[n][0], acc[(MQ)*2+mi][n], 0, 0, 0); \
        acc[(MQ)*2+mi][n] = __builtin_amdgcn_mfma_f32_16x16x32_bf16(fa[mi][1], fb[n][1], acc[(MQ)*2+mi][n], 0, 0, 0); \
      }

#define PH_TAIL \
    __builtin_amdgcn_s_barrier(); \
    asm volatile("s_waitcnt lgkmcnt(0)" ::: "memory"); \
    __builtin_amdgcn_sched_barrier(0); \
    __builtin_amdgcn_s_setprio(1);

  for (int j = 0; j < 32; ++j) {
    const char* Ab = lds + (j & 1) * 65536;
    const char* Bb = Ab + 32768;
    char* An = lds + ((j + 1) & 1) * 65536;
    char* Bn = An + 32768;
    bool st = (j < 31);
    size_t koff = (size_t)(j + 1) * 64;

    short8 fb[4][2];
    // ---- phase 0: burst-stage tile j+1, read all fb + fa(mq=0), 16 MFMA
    {
      if (st) {
        #pragma unroll
        for (int s = 0; s < 4; ++s) gload16(gA + s * 131072 + koff, An + s * 8192 + wsd);
        #pragma unroll
        for (int s = 0; s < 4; ++s) gload16(gB + s * 131072 + koff, Bn + s * 8192 + wsd);
      }
      #pragma unroll
      for (int n = 0; n < 4; ++n)
        #pragma unroll
        for (int kk = 0; kk < 2; ++kk)
          fb[n][kk] = *(const short8*)(Bb + ((boff0 + n * 2048) ^ (kk * 64)));
      short8 fa[2][2];
      READ_FA(0)
      PH_TAIL
      MFMAS(0)
      __builtin_amdgcn_s_setprio(0);
      __builtin_amdgcn_s_barrier();
    }
    // ---- phases 1-2
    {
      short8 fa[2][2];
      READ_FA(1)
      PH_TAIL
      MFMAS(1)
      __builtin_amdgcn_s_setprio(0);
      __builtin_amdgcn_s_barrier();
    }
    {
      short8 fa[2][2];
      READ_FA(2)
      PH_TAIL
      MFMAS(2)
      __builtin_amdgcn_s_setprio(0);
      __builtin_amdgcn_s_barrier();
    }
    // ---- phase 3: drain tile j+1's loads at the end
    {
      short8 fa[2][2];
      READ_FA(3)
      PH_TAIL
      MFMAS(3)
      __builtin_amdgcn_s_setprio(0);
      asm volatile("s_waitcnt vmcnt(0)" ::: "memory");
      __builtin_amdgcn_s_barrier();
    }
  }
#undef READ_FA
#undef MFMAS
#undef PH_TAIL

  // ---- epilogue: Ys (1024 rows (n_local*4+b_local) x 64 cin, swizzled) overlays both bufs
  #pragma unroll
  for (int m = 0; m < 8; ++m) {
    #pragma unroll
    for (int n = 0; n < 4; ++n) {
      #pragma unroll
      for (int reg = 0; reg < 4; ++reg) {
        int nl = wr * 128 + m * 16 + ((lane >> 4) << 2) + reg;   // 0..255
        int cin = n * 16 + (lane & 15);                          // 0..63
        int nb = nl * 4 + wc;                                    // 0..1023
        int byte = nb * 128 + ((cin * 2) ^ ((nb & 7) << 4));
        *(unsigned short*)(lds + byte) = f2bf(acc[m][n][reg]);
      }
    }
  }
  __syncthreads();

  // GEMM2: (1024 x 64) @ (64 x 128) + b, swiglu. W^T from global (L2-hot).
  short8 wf0[8], wf1[8];
  float bl[8];
  #pragma unroll
  for (int f2 = 0; f2 < 8; ++f2) {
    int jc = f2 * 16 + (lane & 15);
    wf0[f2] = *(const short8*)((const char*)WT + jc * 128 + (lane >> 4) * 16);
    wf1[f2] = *(const short8*)((const char*)WT + jc * 128 + 64 + (lane >> 4) * 16);
    bl[f2] = bfc[jc];
  }

  int b0 = pb * 4;
  #pragma unroll
  for (int r2 = 0; r2 < 8; ++r2) {
    int row = wid * 128 + r2 * 16 + (lane & 15);
    int cb = ((lane >> 4) * 16) ^ ((row & 7) << 4);
    short8 a0 = *(const short8*)(lds + (row * 128 + cb));
    short8 a1 = *(const short8*)(lds + (row * 128 + (cb ^ 64)));
    f32x4 acc2[8];
    #pragma unroll
    for (int f2 = 0; f2 < 8; ++f2) {
      acc2[f2] = (f32x4){0.f, 0.f, 0.f, 0.f};
      acc2[f2] = __builtin_amdgcn_mfma_f32_16x16x32_bf16(a0, wf0[f2], acc2[f2], 0, 0, 0);
      acc2[f2] = __builtin_amdgcn_mfma_f32_16x16x32_bf16(a1, wf1[f2], acc2[f2], 0, 0, 0);
    }
    #pragma unroll
    for (int f2 = 0; f2 < 4; ++f2) {
      #pragma unroll
      for (int reg = 0; reg < 4; ++reg) {
        int nb = wid * 128 + r2 * 16 + ((lane >> 4) << 2) + reg;
        float zl = acc2[f2][reg] + bl[f2];
        float zr = acc2[f2 + 4][reg] + bl[f2 + 4];
        float ov = zl * sigf(zr);
        int n = n0 + (nb >> 2);
        int b = b0 + (nb & 3);
        int co = f2 * 16 + (lane & 15);
        out[(size_t)((t * N_DIM + n) * B_DIM + b) * C_OUT + co] = ov;
      }
    }
  }
}

extern "C" void kernel_launch(void* const* d_in, const int* in_sizes, int n_in,
                              void* d_out, int out_size, void* d_ws, size_t ws_size,
                              hipStream_t stream) {
  const float* x  = (const float*)d_in[0];
  const float* As = (const float*)d_in[1];
  const float* E1 = (const float*)d_in[2];
  const float* E2 = (const float*)d_in[3];
  const float* al = (const float*)d_in[4];
  const float* W  = (const float*)d_in[5];
  const float* bf = (const float*)d_in[6];
  float* out = (float*)d_out;

  char* ws = (char*)d_ws;
  unsigned short* XT = (unsigned short*)ws;                       // 50,331,648 B
  unsigned short* Ab = (unsigned short*)(ws + 50331648);          //  8,388,608 B
  unsigned short* WT = (unsigned short*)(ws + 58720256);          //     16,384 B
  float* dinv = (float*)(ws + 58736640);
  float* mx   = (float*)(ws + 58744832);
  float* se   = (float*)(ws + 58753024);

  k_stats<<<dim3(2048), dim3(256), 0, stream>>>(As, E1, E2, dinv, mx, se);
  k_wt<<<dim3(32), dim3(256), 0, stream>>>(W, WT);
  k_abuild<<<dim3(2048), dim3(256), 0, stream>>>(As, E1, E2, al, dinv, mx, se, Ab);
  k_xt<<<dim3(6144), dim3(256), 0, stream>>>(x, XT);
  k_gemm<<<dim3(384), dim3(512), 0, stream>>>(Ab, XT, WT, bf, out);
}